// Round 2
// baseline (504.203 us; speedup 1.0000x reference)
//
#include <hip/hip_runtime.h>
#include <hip/hip_bf16.h>
#include <cstdint>
#include <cstddef>

#define C_N 100000
#define B_N 512
#define D_N 512

#define COS_M_F   0.87758256189037276f
#define SIN_M_F   0.47942553860420301f
#define THRESH_F  (-0.87758256189037276f)
#define MM_F      0.23971276930210150f
#define S_F       64.0f

typedef __attribute__((ext_vector_type(8))) short short8;
typedef __attribute__((ext_vector_type(4))) float f32x4;

__device__ __forceinline__ unsigned short f2bf(float f) {
  unsigned u = __float_as_uint(f);
  u = u + 0x7fffu + ((u >> 16) & 1u);
  return (unsigned short)(u >> 16);
}

__device__ __forceinline__ float wave_sum(float v) {
#pragma unroll
  for (int o = 32; o > 0; o >>= 1) v += __shfl_down(v, o, 64);
  return v;
}

__device__ __forceinline__ void lds_load16(const void* g, void* l) {
  __builtin_amdgcn_global_load_lds(
      (const __attribute__((address_space(1))) unsigned int*)g,
      (__attribute__((address_space(3))) unsigned int*)l, 16, 0, 0);
}

// =====================  NEW PATH  ============================================
// ---------------- kernel N1: fused col-norm + normalize + transpose -> Knt ---
// Knt[j][d] = bf16(K[d][j] * rsqrt(sum_d K[d][j]^2)), C padded to 100096 rows.
#define TCOLS 64
#define TSTR 514  // LDS row stride in bf16 elems; 1028B -> word stride 257 (odd) => phase-2 writes conflict-free

__launch_bounds__(256)
__global__ void knorm_t_k(const float* __restrict__ Kp, float* __restrict__ cninv,
                          unsigned short* __restrict__ Knt) {
  __shared__ __align__(16) unsigned short Tl[TCOLS * TSTR];  // 65792 B
  __shared__ float ssum[4][TCOLS];
  __shared__ float cns[TCOLS];
  const int t = threadIdx.x;
  const int j0 = blockIdx.x * TCOLS;
  const int jl = t & 63;
  const int dw = t >> 6;  // 0..3
  const int j = j0 + jl;
  const bool jok = (j < C_N);

  // phase 1: column sum-of-squares (coalesced 256B/wave rows)
  float ss = 0.f;
  for (int d = dw; d < D_N; d += 4) {
    float v = jok ? Kp[(size_t)d * C_N + j] : 0.f;
    ss += v * v;
  }
  ssum[dw][jl] = ss;
  __syncthreads();
  if (t < TCOLS) {
    float s = ssum[0][t] + ssum[1][t] + ssum[2][t] + ssum[3][t];
    float r = rsqrtf(fmaxf(s, 1e-30f));
    cns[t] = r;
    if (j0 + t < C_N) cninv[j0 + t] = r;
  }
  __syncthreads();

  // phase 2: re-read (L2-hit), scale, bf16, store transposed-in-LDS
  const float r = cns[jl];
  for (int d = dw; d < D_N; d += 4) {
    float v = jok ? Kp[(size_t)d * C_N + j] : 0.f;
    Tl[jl * TSTR + d] = f2bf(v * r);
  }
  __syncthreads();

  // phase 3: write Knt rows (coalesced 16B/lane)
  const int chunk = t & 63;
#pragma unroll
  for (int rr = 0; rr < 16; ++rr) {
    int jj = rr * 4 + dw;
    int jg = j0 + jj;
    uint vv[4];
#pragma unroll
    for (int k2 = 0; k2 < 4; ++k2)
      vv[k2] = *(const uint*)(&Tl[jj * TSTR + chunk * 8 + k2 * 2]);
    uint4 v = make_uint4(vv[0], vv[1], vv[2], vv[3]);
    if (jg < C_N)
      *(uint4*)(&Knt[(size_t)jg * D_N + chunk * 8]) = v;
  }
}

// ---------------- kernel 2: embedding row normalize -> bf16 ------------------
__global__ void embnorm_k(const float* __restrict__ emb, unsigned short* __restrict__ embn,
                          float* __restrict__ rinv) {
  int row = blockIdx.x;
  int t = threadIdx.x;  // 128 threads, one float4 each
  float4 v = ((const float4*)(emb + (size_t)row * D_N))[t];
  float ss = v.x * v.x + v.y * v.y + v.z * v.z + v.w * v.w;
  ss = wave_sum(ss);
  __shared__ float red[2];
  if ((t & 63) == 0) red[t >> 6] = ss;
  __syncthreads();
  float tot = red[0] + red[1];
  float ri = rsqrtf(tot);
  if (t == 0) rinv[row] = ri;
  ushort4 o;
  o.x = f2bf(v.x * ri); o.y = f2bf(v.y * ri); o.z = f2bf(v.z * ri); o.w = f2bf(v.w * ri);
  ((ushort4*)(embn + (size_t)row * D_N))[t] = o;
}

// ---------------- kernel 3: per-row target logit (f32, exact path) -----------
__global__ void target_k(const float* __restrict__ emb, const float* __restrict__ Kp,
                         const float* __restrict__ cninv, const float* __restrict__ rinv,
                         const int* __restrict__ labels,
                         float* __restrict__ target, float* __restrict__ ctm,
                         float* __restrict__ ft) {
  int row = blockIdx.x;
  int t = threadIdx.x;  // 256
  int lab = labels[row];
  float p = 0.f;
  for (int d = t; d < D_N; d += 256)
    p += emb[(size_t)row * D_N + d] * Kp[(size_t)d * C_N + lab];
  p = wave_sum(p);
  __shared__ float red[4];
  if ((t & 63) == 0) red[t >> 6] = p;
  __syncthreads();
  if (t == 0) {
    float dot = red[0] + red[1] + red[2] + red[3];
    float tg = dot * rinv[row] * cninv[lab];
    tg = fminf(fmaxf(tg, -1.f), 1.f);
    float st = sqrtf(fmaxf(1.f - tg * tg, 0.f));
    float cm = tg * COS_M_F - st * SIN_M_F;
    float f = (tg > THRESH_F) ? cm : (tg - MM_F);
    target[row] = tg;
    ctm[row] = cm;
    ft[row] = f;
  }
}

// ---------------- kernel 4: new_t reduction ----------------------------------
__global__ void newt_k(const float* __restrict__ target, const float* __restrict__ t_in,
                       float* __restrict__ newt) {
  int t = threadIdx.x;  // 512
  float v = target[t];
  v = wave_sum(v);
  __shared__ float red[8];
  if ((t & 63) == 0) red[t >> 6] = v;
  __syncthreads();
  if (t == 0) {
    float s = 0.f;
#pragma unroll
    for (int i = 0; i < 8; ++i) s += red[i];
    *newt = 0.01f * (s / (float)B_N) + 0.99f * t_in[0];
  }
}

// ---------------- kernel N5: MFMA GEMM, global_load_lds + swizzle + dbuf -----
// BM=512 (K read once), BN=64, BK=32. 8 waves (4M x 2N), wave tile 128x32.
// LDS is lane-linear 16B chunks; swizzle applied on global SOURCE (staging)
// and on ds_read addresses (rule 21). Chunk map per row-pair (8 chunks):
//   slot3 = (((row&1)<<2)|kc) ^ ((row>>1)&7); byte = (row>>1)*128 + slot3*16
__launch_bounds__(512, 4)
__global__ void gemm2_k(const unsigned short* __restrict__ embn,
                        const unsigned short* __restrict__ Knt,
                        const int* __restrict__ labels,
                        const float* __restrict__ ctm, const float* __restrict__ ft,
                        const float* __restrict__ newt_p, float* __restrict__ out) {
  __shared__ __align__(16) unsigned short Alds[2][B_N * 32];  // 2 x 32 KiB
  __shared__ __align__(16) unsigned short Blds[2][64 * 32];   // 2 x 4 KiB
  __shared__ int   slab[B_N];
  __shared__ float sctm[B_N];
  __shared__ float sft[B_N];

  const int t = threadIdx.x;
  const int j0 = blockIdx.x * 64;

  slab[t] = labels[t];
  sctm[t] = ctm[t];
  sft[t]  = ft[t];

  const int l = t & 63, w = t >> 6;
  const int wr = w >> 1, wc = w & 1;
  const int lq = l >> 4, lr = l & 15;

  // staging decode: lane-linear chunk -> (row offset r0, k-chunk kc)
  const int sidx = (l & 7) ^ (l >> 3);
  const int r0 = ((l >> 3) << 1) | (sidx >> 2);
  const int kc8 = (sidx & 3) * 8;

  const unsigned short* asrc = embn + (size_t)(w * 64 + r0) * D_N + kc8;
  const unsigned short* bsrc = Knt + (size_t)(j0 + w * 16 + r0) * D_N + kc8;  // used when w<4

  // read-side swizzle pieces
  const int s16 = ((((lr & 1) << 2) | lq) ^ (lr >> 1)) << 4;  // slot byte offset
  const int rh = lr >> 1;

  const float newt = *newt_p;
  const int jn0 = j0 + wc * 32 + lr;
  const int jn1 = jn0 + 16;

  f32x4 acc[8][2];
#pragma unroll
  for (int mb = 0; mb < 8; ++mb) {
    acc[mb][0] = 0;
    acc[mb][1] = 0;
  }

  // prologue: stage k0=0 into buffer 0
#pragma unroll
  for (int p = 0; p < 4; ++p)
    lds_load16(asrc + p * 16 * D_N, &Alds[0][w * 2048 + p * 512]);
  if (w < 4) lds_load16(bsrc, &Blds[0][w * 512]);
  __syncthreads();

#pragma unroll
  for (int it = 0; it < 16; ++it) {
    const int cur = it & 1, nxt = cur ^ 1;
    if (it < 15) {
      const int k0 = (it + 1) * 32;
#pragma unroll
      for (int p = 0; p < 4; ++p)
        lds_load16(asrc + p * 16 * D_N + k0, &Alds[nxt][w * 2048 + p * 512]);
      if (w < 4) lds_load16(bsrc + k0, &Blds[nxt][w * 512]);
    }
    const char* Ab = (const char*)Alds[cur];
    const char* Bb = (const char*)Blds[cur];
    short8 b0 = *(const short8*)(Bb + (((wc * 16 + 0 + rh) << 7) + s16));
    short8 b1 = *(const short8*)(Bb + (((wc * 16 + 8 + rh) << 7) + s16));
#pragma unroll
    for (int mb = 0; mb < 8; ++mb) {
      short8 a = *(const short8*)(Ab + (((wr * 64 + mb * 8 + rh) << 7) + s16));
      acc[mb][0] = __builtin_amdgcn_mfma_f32_16x16x32_bf16(a, b0, acc[mb][0], 0, 0, 0);
      acc[mb][1] = __builtin_amdgcn_mfma_f32_16x16x32_bf16(a, b1, acc[mb][1], 0, 0, 0);
    }
    __syncthreads();
  }

  // epilogue: c/d layout col = lane&15, row = (lane>>4)*4 + r
#pragma unroll
  for (int mb = 0; mb < 8; ++mb) {
    int ibase = wr * 128 + mb * 16 + 4 * lq;
#pragma unroll
    for (int r = 0; r < 4; ++r) {
      int i = ibase + r;
      int lab = slab[i];
      float cm = sctm[i];
      float f = sft[i];
      {
        float c = fminf(fmaxf(acc[mb][0][r], -1.f), 1.f);
        float o = (c > cm) ? c * (newt + c) : c;
        o = (jn0 == lab) ? f : o;
        if (jn0 < C_N) out[(size_t)i * C_N + jn0] = o * S_F;
      }
      {
        float c = fminf(fmaxf(acc[mb][1][r], -1.f), 1.f);
        float o = (c > cm) ? c * (newt + c) : c;
        o = (jn1 == lab) ? f : o;
        if (jn1 < C_N) out[(size_t)i * C_N + jn1] = o * S_F;
      }
    }
  }
}

// =====================  FALLBACK PATH (round-1, verified)  ===================
#define JV (C_N / 4)
#define DSPLIT 8
#define DCH (D_N / DSPLIT)

__global__ void colnorm_part_k(const float* __restrict__ Kp, float4* __restrict__ part) {
  int j4 = blockIdx.x * blockDim.x + threadIdx.x;
  if (j4 >= JV) return;
  int db = blockIdx.y;
  const float4* Kv = (const float4*)Kp;
  float4 s = make_float4(0.f, 0.f, 0.f, 0.f);
  int d0 = db * DCH;
  for (int d = d0; d < d0 + DCH; ++d) {
    float4 v = Kv[(size_t)d * JV + j4];
    s.x += v.x * v.x; s.y += v.y * v.y; s.z += v.z * v.z; s.w += v.w * v.w;
  }
  part[(size_t)db * JV + j4] = s;
}

__global__ void colnorm_fin_k(const float4* __restrict__ part, float4* __restrict__ cninv4) {
  int j4 = blockIdx.x * blockDim.x + threadIdx.x;
  if (j4 >= JV) return;
  float4 s = make_float4(0.f, 0.f, 0.f, 0.f);
#pragma unroll
  for (int db = 0; db < DSPLIT; ++db) {
    float4 v = part[(size_t)db * JV + j4];
    s.x += v.x; s.y += v.y; s.z += v.z; s.w += v.w;
  }
  float4 r;
  r.x = rsqrtf(s.x); r.y = rsqrtf(s.y); r.z = rsqrtf(s.z); r.w = rsqrtf(s.w);
  cninv4[j4] = r;
}

#define BN 64
#define BK 32
#define PAD 40

__launch_bounds__(512)
__global__ void gemm_k(const unsigned short* __restrict__ embn, const float* __restrict__ Kp,
                       const float* __restrict__ cninv, const int* __restrict__ labels,
                       const float* __restrict__ ctm, const float* __restrict__ ft,
                       const float* __restrict__ newt_p, float* __restrict__ out) {
  __shared__ __align__(16) unsigned short Alds[B_N * PAD];
  __shared__ __align__(16) unsigned short Blds[BN * PAD];
  __shared__ int   slab[B_N];
  __shared__ float sctm[B_N];
  __shared__ float sft[B_N];

  const int t = threadIdx.x;
  const int j0 = blockIdx.x * BN;

  slab[t] = labels[t];
  sctm[t] = ctm[t];
  sft[t]  = ft[t];

  const int l = t & 63, w = t >> 6;
  const int wr = w >> 1, wc = w & 1;
  const int lq = l >> 4, lr = l & 15;

  const float newt = *newt_p;
  const int jn0 = j0 + wc * 32 + lr;
  const int jn1 = jn0 + 16;
  const float cn0 = (jn0 < C_N) ? cninv[jn0] : 0.f;
  const float cn1 = (jn1 < C_N) ? cninv[jn1] : 0.f;

  f32x4 acc[8][2];
#pragma unroll
  for (int mb = 0; mb < 8; ++mb) {
    acc[mb][0] = 0;
    acc[mb][1] = 0;
  }

  const int arow_s = t >> 2;
  const int ac8 = (t & 3) * 8;
  const int bn = t & 63;
  const int bq = t >> 6;
  const int bj = j0 + bn;
  const bool bj_ok = (bj < C_N);

  for (int k0 = 0; k0 < D_N; k0 += BK) {
#pragma unroll
    for (int p = 0; p < 4; ++p) {
      int row = arow_s + 128 * p;
      uint4 v = *(const uint4*)(embn + (size_t)row * D_N + k0 + ac8);
      *(uint4*)(&Alds[row * PAD + ac8]) = v;
    }
#pragma unroll
    for (int p = 0; p < 2; ++p) {
      int q = bq + 8 * p;
      int kk = 2 * q;
      float f0 = bj_ok ? Kp[(size_t)(k0 + kk) * C_N + bj] : 0.f;
      float f1 = bj_ok ? Kp[(size_t)(k0 + kk + 1) * C_N + bj] : 0.f;
      unsigned u0 = f2bf(f0);
      unsigned u1 = f2bf(f1);
      *(unsigned*)(&Blds[bn * PAD + kk]) = u0 | (u1 << 16);
    }
    __syncthreads();

    short8 a[8];
#pragma unroll
    for (int mb = 0; mb < 8; ++mb) {
      int arow = wr * 128 + mb * 16 + lr;
      a[mb] = *(const short8*)(&Alds[arow * PAD + lq * 8]);
    }
    short8 b0 = *(const short8*)(&Blds[(wc * 32 + lr) * PAD + lq * 8]);
    short8 b1 = *(const short8*)(&Blds[(wc * 32 + 16 + lr) * PAD + lq * 8]);
#pragma unroll
    for (int mb = 0; mb < 8; ++mb) {
      acc[mb][0] = __builtin_amdgcn_mfma_f32_16x16x32_bf16(a[mb], b0, acc[mb][0], 0, 0, 0);
      acc[mb][1] = __builtin_amdgcn_mfma_f32_16x16x32_bf16(a[mb], b1, acc[mb][1], 0, 0, 0);
    }
    __syncthreads();
  }

#pragma unroll
  for (int mb = 0; mb < 8; ++mb) {
    int ibase = wr * 128 + mb * 16 + 4 * lq;
#pragma unroll
    for (int r = 0; r < 4; ++r) {
      int i = ibase + r;
      int lab = slab[i];
      float cm = sctm[i];
      float f = sft[i];
      {
        float c = acc[mb][0][r] * cn0;
        c = fminf(fmaxf(c, -1.f), 1.f);
        float o = (c > cm) ? c * (newt + c) : c;
        o = (jn0 == lab) ? f : o;
        if (jn0 < C_N) out[(size_t)i * C_N + jn0] = o * S_F;
      }
      {
        float c = acc[mb][1][r] * cn1;
        c = fminf(fmaxf(c, -1.f), 1.f);
        float o = (c > cm) ? c * (newt + c) : c;
        o = (jn1 == lab) ? f : o;
        if (jn1 < C_N) out[(size_t)i * C_N + jn1] = o * S_F;
      }
    }
  }
}

// ---------------- launch -----------------------------------------------------
extern "C" void kernel_launch(void* const* d_in, const int* in_sizes, int n_in,
                              void* d_out, int out_size, void* d_ws, size_t ws_size,
                              hipStream_t stream) {
  (void)in_sizes; (void)n_in; (void)out_size;
  const float* emb = (const float*)d_in[0];
  const int* labels = (const int*)d_in[1];
  const float* Kp = (const float*)d_in[2];
  const float* t_in = (const float*)d_in[3];
  float* out = (float*)d_out;

  char* wsp = (char*)d_ws;
  const size_t KNT_BYTES = (size_t)100096 * D_N * 2;  // 102,498,304
  const size_t NEED = KNT_BYTES + 524288 + 400000 + 4 * 2048 + 4;

  if (ws_size >= NEED) {
    unsigned short* Knt = (unsigned short*)(wsp + 0);
    unsigned short* embn = (unsigned short*)(wsp + KNT_BYTES);
    float* cninv = (float*)(wsp + KNT_BYTES + 524288);
    float* target = (float*)(wsp + KNT_BYTES + 524288 + 400000);
    float* ctm    = (float*)(wsp + KNT_BYTES + 524288 + 400000 + 2048);
    float* ft     = (float*)(wsp + KNT_BYTES + 524288 + 400000 + 2 * 2048);
    float* rinv   = (float*)(wsp + KNT_BYTES + 524288 + 400000 + 3 * 2048);
    float* newt   = (float*)(wsp + KNT_BYTES + 524288 + 400000 + 4 * 2048);

    knorm_t_k<<<(C_N + TCOLS - 1) / TCOLS, 256, 0, stream>>>(Kp, cninv, Knt);
    embnorm_k<<<B_N, 128, 0, stream>>>(emb, embn, rinv);
    target_k<<<B_N, 256, 0, stream>>>(emb, Kp, cninv, rinv, labels, target, ctm, ft);
    newt_k<<<1, 512, 0, stream>>>(target, t_in, newt);
    gemm2_k<<<(C_N + 63) / 64, 512, 0, stream>>>(embn, Knt, labels, ctm, ft, newt, out);
  } else {
    unsigned short* embn = (unsigned short*)(wsp + 0);
    float* cninv = (float*)(wsp + 524288);
    float4* part = (float4*)(wsp + 924288);
    float* target = (float*)(wsp + 4124288);
    float* ctm    = (float*)(wsp + 4126336);
    float* ft     = (float*)(wsp + 4128384);
    float* rinv   = (float*)(wsp + 4130432);
    float* newt   = (float*)(wsp + 4132480);

    dim3 cg((JV + 255) / 256, DSPLIT);
    colnorm_part_k<<<cg, 256, 0, stream>>>(Kp, part);
    colnorm_fin_k<<<(JV + 255) / 256, 256, 0, stream>>>(part, (float4*)cninv);
    embnorm_k<<<B_N, 128, 0, stream>>>(emb, embn, rinv);
    target_k<<<B_N, 256, 0, stream>>>(emb, Kp, cninv, rinv, labels, target, ctm, ft);
    newt_k<<<1, 512, 0, stream>>>(target, t_in, newt);
    gemm_k<<<(C_N + BN - 1) / BN, 512, 0, stream>>>(embn, Kp, cninv, labels, ctm, ft, newt, out);
  }
}

// Round 3
// 193.558 us; speedup vs baseline: 2.6049x; 2.6049x over previous
//
#include <hip/hip_runtime.h>
#include <hip/hip_bf16.h>
#include <cstdint>
#include <cstddef>

#define C_N 100000
#define B_N 512
#define D_N 512

#define COS_M_F   0.87758256189037276f
#define SIN_M_F   0.47942553860420301f
#define THRESH_F  (-0.87758256189037276f)
#define MM_F      0.23971276930210150f
#define S_F       64.0f

typedef __attribute__((ext_vector_type(8))) short short8;
typedef __attribute__((ext_vector_type(4))) float f32x4;

__device__ __forceinline__ unsigned short f2bf(float f) {
  unsigned u = __float_as_uint(f);
  u = u + 0x7fffu + ((u >> 16) & 1u);
  return (unsigned short)(u >> 16);
}

__device__ __forceinline__ float wave_sum(float v) {
#pragma unroll
  for (int o = 32; o > 0; o >>= 1) v += __shfl_down(v, o, 64);
  return v;
}

__device__ __forceinline__ void lds_load16(const void* g, void* l) {
  __builtin_amdgcn_global_load_lds(
      (const __attribute__((address_space(1))) unsigned int*)g,
      (__attribute__((address_space(3))) unsigned int*)l, 16, 0, 0);
}

// =====================  NEW PATH  ============================================
// ---------------- kernel N1v2: col-norm + scale + transpose, single K read ---
// Per block: 64 columns, all 512 d. Each thread holds 16 float4 (4 cols x 16 d)
// in registers. Sum-squares via 8KB LDS reduce; scale+bf16 in-register;
// register 4x4 transpose -> 64KB LDS tile [64 j][512 d] with XOR-16B-chunk
// swizzle (ch ^= j&7); phase-3 writes Knt rows as 8 x 128B segments per j.
__launch_bounds__(512)
__global__ void knorm2_k(const float* __restrict__ Kp, float* __restrict__ cninv,
                         unsigned short* __restrict__ Knt) {
  __shared__ __align__(16) unsigned short Tl[64 * 512];  // 65536 B, swizzled chunks
  __shared__ float ssum[32][64];                         // 8 KB
  __shared__ float cns[64];

  const int t = threadIdx.x;
  const int j0 = blockIdx.x * 64;
  const int jq = t & 15;   // 16 float4-column groups
  const int dr = t >> 4;   // 32 d-groups of 16
  const int jcol = min((j0 >> 2) + jq, (C_N >> 2) - 1);  // clamp last block
  const float4* __restrict__ Kv = (const float4*)Kp;

  // phase 1: load 16 rows x float4 (independent, 4x256B per wave instr)
  float4 v[16];
#pragma unroll
  for (int i = 0; i < 16; ++i)
    v[i] = Kv[(size_t)(dr * 16 + i) * (C_N / 4) + jcol];

  float s0 = 0.f, s1 = 0.f, s2 = 0.f, s3 = 0.f;
#pragma unroll
  for (int i = 0; i < 16; ++i) {
    s0 = fmaf(v[i].x, v[i].x, s0);
    s1 = fmaf(v[i].y, v[i].y, s1);
    s2 = fmaf(v[i].z, v[i].z, s2);
    s3 = fmaf(v[i].w, v[i].w, s3);
  }
  ssum[dr][jq * 4 + 0] = s0;
  ssum[dr][jq * 4 + 1] = s1;
  ssum[dr][jq * 4 + 2] = s2;
  ssum[dr][jq * 4 + 3] = s3;
  __syncthreads();
  if (t < 64) {
    float s = 0.f;
#pragma unroll
    for (int d = 0; d < 32; ++d) s += ssum[d][t];
    float r = rsqrtf(fmaxf(s, 1e-30f));
    cns[t] = r;
    if (j0 + t < C_N) cninv[j0 + t] = r;
  }
  __syncthreads();

  // phase 2: scale, bf16, register 4x4 transpose, swizzled LDS write (8B)
  const float r0 = cns[jq * 4 + 0];
  const float r1 = cns[jq * 4 + 1];
  const float r2 = cns[jq * 4 + 2];
  const float r3 = cns[jq * 4 + 3];
#pragma unroll
  for (int g = 0; g < 4; ++g) {          // d-quads: d = dr*16 + g*4 + q
    const int ch = dr * 2 + (g >> 1);    // logical 16B chunk in row
    const int sub = (g & 1) * 8;         // byte offset within chunk
#pragma unroll
    for (int c = 0; c < 4; ++c) {
      const int j = jq * 4 + c;
      const float rc = (c == 0) ? r0 : (c == 1) ? r1 : (c == 2) ? r2 : r3;
      unsigned lo, hi;
      lo = (unsigned)f2bf(v[g * 4 + 0][c] * rc) | ((unsigned)f2bf(v[g * 4 + 1][c] * rc) << 16);
      hi = (unsigned)f2bf(v[g * 4 + 2][c] * rc) | ((unsigned)f2bf(v[g * 4 + 3][c] * rc) << 16);
      const int phys = ch ^ (j & 7);
      *(uint2*)((char*)Tl + j * 1024 + phys * 16 + sub) = make_uint2(lo, hi);
    }
  }
  __syncthreads();

  // phase 3: write Knt rows; lane l: jr=l>>3 (8 rows/wave), dc=l&7 (8x16B per row)
  const int jr = t >> 3;
  const int dc = t & 7;
  const int jg = j0 + jr;
  if (jg < C_N) {
#pragma unroll
    for (int s = 0; s < 8; ++s) {
      const int phys = (s * 8) + (dc ^ (jr & 7));  // XOR low-3 of chunk
      uint4 val = *(const uint4*)((const char*)Tl + jr * 1024 + phys * 16);
      *(uint4*)(&Knt[(size_t)jg * D_N + s * 64 + dc * 8]) = val;
    }
  }
}

// ---------------- kernel 2: embedding row normalize -> bf16 ------------------
__global__ void embnorm_k(const float* __restrict__ emb, unsigned short* __restrict__ embn,
                          float* __restrict__ rinv) {
  int row = blockIdx.x;
  int t = threadIdx.x;  // 128 threads, one float4 each
  float4 v = ((const float4*)(emb + (size_t)row * D_N))[t];
  float ss = v.x * v.x + v.y * v.y + v.z * v.z + v.w * v.w;
  ss = wave_sum(ss);
  __shared__ float red[2];
  if ((t & 63) == 0) red[t >> 6] = ss;
  __syncthreads();
  float tot = red[0] + red[1];
  float ri = rsqrtf(tot);
  if (t == 0) rinv[row] = ri;
  ushort4 o;
  o.x = f2bf(v.x * ri); o.y = f2bf(v.y * ri); o.z = f2bf(v.z * ri); o.w = f2bf(v.w * ri);
  ((ushort4*)(embn + (size_t)row * D_N))[t] = o;
}

// ---------------- kernel 3: per-row target logit (f32, exact path) -----------
__global__ void target_k(const float* __restrict__ emb, const float* __restrict__ Kp,
                         const float* __restrict__ cninv, const float* __restrict__ rinv,
                         const int* __restrict__ labels,
                         float* __restrict__ target, float* __restrict__ ctm,
                         float* __restrict__ ft) {
  int row = blockIdx.x;
  int t = threadIdx.x;  // 256
  int lab = labels[row];
  float p = 0.f;
  for (int d = t; d < D_N; d += 256)
    p += emb[(size_t)row * D_N + d] * Kp[(size_t)d * C_N + lab];
  p = wave_sum(p);
  __shared__ float red[4];
  if ((t & 63) == 0) red[t >> 6] = p;
  __syncthreads();
  if (t == 0) {
    float dot = red[0] + red[1] + red[2] + red[3];
    float tg = dot * rinv[row] * cninv[lab];
    tg = fminf(fmaxf(tg, -1.f), 1.f);
    float st = sqrtf(fmaxf(1.f - tg * tg, 0.f));
    float cm = tg * COS_M_F - st * SIN_M_F;
    float f = (tg > THRESH_F) ? cm : (tg - MM_F);
    target[row] = tg;
    ctm[row] = cm;
    ft[row] = f;
  }
}

// ---------------- kernel 4: new_t reduction ----------------------------------
__global__ void newt_k(const float* __restrict__ target, const float* __restrict__ t_in,
                       float* __restrict__ newt) {
  int t = threadIdx.x;  // 512
  float v = target[t];
  v = wave_sum(v);
  __shared__ float red[8];
  if ((t & 63) == 0) red[t >> 6] = v;
  __syncthreads();
  if (t == 0) {
    float s = 0.f;
#pragma unroll
    for (int i = 0; i < 8; ++i) s += red[i];
    *newt = 0.01f * (s / (float)B_N) + 0.99f * t_in[0];
  }
}

// ---------------- kernel N5: MFMA GEMM, global_load_lds + swizzle + dbuf -----
// (unchanged from round 2 — verified, ~80us)
__launch_bounds__(512, 4)
__global__ void gemm2_k(const unsigned short* __restrict__ embn,
                        const unsigned short* __restrict__ Knt,
                        const int* __restrict__ labels,
                        const float* __restrict__ ctm, const float* __restrict__ ft,
                        const float* __restrict__ newt_p, float* __restrict__ out) {
  __shared__ __align__(16) unsigned short Alds[2][B_N * 32];  // 2 x 32 KiB
  __shared__ __align__(16) unsigned short Blds[2][64 * 32];   // 2 x 4 KiB
  __shared__ int   slab[B_N];
  __shared__ float sctm[B_N];
  __shared__ float sft[B_N];

  const int t = threadIdx.x;
  const int j0 = blockIdx.x * 64;

  slab[t] = labels[t];
  sctm[t] = ctm[t];
  sft[t]  = ft[t];

  const int l = t & 63, w = t >> 6;
  const int wr = w >> 1, wc = w & 1;
  const int lq = l >> 4, lr = l & 15;

  const int sidx = (l & 7) ^ (l >> 3);
  const int r0 = ((l >> 3) << 1) | (sidx >> 2);
  const int kc8 = (sidx & 3) * 8;

  const unsigned short* asrc = embn + (size_t)(w * 64 + r0) * D_N + kc8;
  const unsigned short* bsrc = Knt + (size_t)(j0 + w * 16 + r0) * D_N + kc8;

  const int s16 = ((((lr & 1) << 2) | lq) ^ (lr >> 1)) << 4;
  const int rh = lr >> 1;

  const float newt = *newt_p;
  const int jn0 = j0 + wc * 32 + lr;
  const int jn1 = jn0 + 16;

  f32x4 acc[8][2];
#pragma unroll
  for (int mb = 0; mb < 8; ++mb) {
    acc[mb][0] = 0;
    acc[mb][1] = 0;
  }

#pragma unroll
  for (int p = 0; p < 4; ++p)
    lds_load16(asrc + p * 16 * D_N, &Alds[0][w * 2048 + p * 512]);
  if (w < 4) lds_load16(bsrc, &Blds[0][w * 512]);
  __syncthreads();

#pragma unroll
  for (int it = 0; it < 16; ++it) {
    const int cur = it & 1, nxt = cur ^ 1;
    if (it < 15) {
      const int k0 = (it + 1) * 32;
#pragma unroll
      for (int p = 0; p < 4; ++p)
        lds_load16(asrc + p * 16 * D_N + k0, &Alds[nxt][w * 2048 + p * 512]);
      if (w < 4) lds_load16(bsrc + k0, &Blds[nxt][w * 512]);
    }
    const char* Ab = (const char*)Alds[cur];
    const char* Bb = (const char*)Blds[cur];
    short8 b0 = *(const short8*)(Bb + (((wc * 16 + 0 + rh) << 7) + s16));
    short8 b1 = *(const short8*)(Bb + (((wc * 16 + 8 + rh) << 7) + s16));
#pragma unroll
    for (int mb = 0; mb < 8; ++mb) {
      short8 a = *(const short8*)(Ab + (((wr * 64 + mb * 8 + rh) << 7) + s16));
      acc[mb][0] = __builtin_amdgcn_mfma_f32_16x16x32_bf16(a, b0, acc[mb][0], 0, 0, 0);
      acc[mb][1] = __builtin_amdgcn_mfma_f32_16x16x32_bf16(a, b1, acc[mb][1], 0, 0, 0);
    }
    __syncthreads();
  }

#pragma unroll
  for (int mb = 0; mb < 8; ++mb) {
    int ibase = wr * 128 + mb * 16 + 4 * lq;
#pragma unroll
    for (int r = 0; r < 4; ++r) {
      int i = ibase + r;
      int lab = slab[i];
      float cm = sctm[i];
      float f = sft[i];
      {
        float c = fminf(fmaxf(acc[mb][0][r], -1.f), 1.f);
        float o = (c > cm) ? c * (newt + c) : c;
        o = (jn0 == lab) ? f : o;
        if (jn0 < C_N) out[(size_t)i * C_N + jn0] = o * S_F;
      }
      {
        float c = fminf(fmaxf(acc[mb][1][r], -1.f), 1.f);
        float o = (c > cm) ? c * (newt + c) : c;
        o = (jn1 == lab) ? f : o;
        if (jn1 < C_N) out[(size_t)i * C_N + jn1] = o * S_F;
      }
    }
  }
}

// =====================  FALLBACK PATH (round-1, verified)  ===================
#define JV (C_N / 4)
#define DSPLIT 8
#define DCH (D_N / DSPLIT)

__global__ void colnorm_part_k(const float* __restrict__ Kp, float4* __restrict__ part) {
  int j4 = blockIdx.x * blockDim.x + threadIdx.x;
  if (j4 >= JV) return;
  int db = blockIdx.y;
  const float4* Kv = (const float4*)Kp;
  float4 s = make_float4(0.f, 0.f, 0.f, 0.f);
  int d0 = db * DCH;
  for (int d = d0; d < d0 + DCH; ++d) {
    float4 v = Kv[(size_t)d * JV + j4];
    s.x += v.x * v.x; s.y += v.y * v.y; s.z += v.z * v.z; s.w += v.w * v.w;
  }
  part[(size_t)db * JV + j4] = s;
}

__global__ void colnorm_fin_k(const float4* __restrict__ part, float4* __restrict__ cninv4) {
  int j4 = blockIdx.x * blockDim.x + threadIdx.x;
  if (j4 >= JV) return;
  float4 s = make_float4(0.f, 0.f, 0.f, 0.f);
#pragma unroll
  for (int db = 0; db < DSPLIT; ++db) {
    float4 v = part[(size_t)db * JV + j4];
    s.x += v.x; s.y += v.y; s.z += v.z; s.w += v.w;
  }
  float4 r;
  r.x = rsqrtf(s.x); r.y = rsqrtf(s.y); r.z = rsqrtf(s.z); r.w = rsqrtf(s.w);
  cninv4[j4] = r;
}

#define BN 64
#define BK 32
#define PAD 40

__launch_bounds__(512)
__global__ void gemm_k(const unsigned short* __restrict__ embn, const float* __restrict__ Kp,
                       const float* __restrict__ cninv, const int* __restrict__ labels,
                       const float* __restrict__ ctm, const float* __restrict__ ft,
                       const float* __restrict__ newt_p, float* __restrict__ out) {
  __shared__ __align__(16) unsigned short Alds[B_N * PAD];
  __shared__ __align__(16) unsigned short Blds[BN * PAD];
  __shared__ int   slab[B_N];
  __shared__ float sctm[B_N];
  __shared__ float sft[B_N];

  const int t = threadIdx.x;
  const int j0 = blockIdx.x * BN;

  slab[t] = labels[t];
  sctm[t] = ctm[t];
  sft[t]  = ft[t];

  const int l = t & 63, w = t >> 6;
  const int wr = w >> 1, wc = w & 1;
  const int lq = l >> 4, lr = l & 15;

  const float newt = *newt_p;
  const int jn0 = j0 + wc * 32 + lr;
  const int jn1 = jn0 + 16;
  const float cn0 = (jn0 < C_N) ? cninv[jn0] : 0.f;
  const float cn1 = (jn1 < C_N) ? cninv[jn1] : 0.f;

  f32x4 acc[8][2];
#pragma unroll
  for (int mb = 0; mb < 8; ++mb) {
    acc[mb][0] = 0;
    acc[mb][1] = 0;
  }

  const int arow_s = t >> 2;
  const int ac8 = (t & 3) * 8;
  const int bn = t & 63;
  const int bq = t >> 6;
  const int bj = j0 + bn;
  const bool bj_ok = (bj < C_N);

  for (int k0 = 0; k0 < D_N; k0 += BK) {
#pragma unroll
    for (int p = 0; p < 4; ++p) {
      int row = arow_s + 128 * p;
      uint4 v = *(const uint4*)(embn + (size_t)row * D_N + k0 + ac8);
      *(uint4*)(&Alds[row * PAD + ac8]) = v;
    }
#pragma unroll
    for (int p = 0; p < 2; ++p) {
      int q = bq + 8 * p;
      int kk = 2 * q;
      float f0 = bj_ok ? Kp[(size_t)(k0 + kk) * C_N + bj] : 0.f;
      float f1 = bj_ok ? Kp[(size_t)(k0 + kk + 1) * C_N + bj] : 0.f;
      unsigned u0 = f2bf(f0);
      unsigned u1 = f2bf(f1);
      *(unsigned*)(&Blds[bn * PAD + kk]) = u0 | (u1 << 16);
    }
    __syncthreads();

    short8 a[8];
#pragma unroll
    for (int mb = 0; mb < 8; ++mb) {
      int arow = wr * 128 + mb * 16 + lr;
      a[mb] = *(const short8*)(&Alds[arow * PAD + lq * 8]);
    }
    short8 b0 = *(const short8*)(&Blds[(wc * 32 + lr) * PAD + lq * 8]);
    short8 b1 = *(const short8*)(&Blds[(wc * 32 + 16 + lr) * PAD + lq * 8]);
#pragma unroll
    for (int mb = 0; mb < 8; ++mb) {
      acc[mb][0] = __builtin_amdgcn_mfma_f32_16x16x32_bf16(a[mb], b0, acc[mb][0], 0, 0, 0);
      acc[mb][1] = __builtin_amdgcn_mfma_f32_16x16x32_bf16(a[mb], b1, acc[mb][1], 0, 0, 0);
    }
    __syncthreads();
  }

#pragma unroll
  for (int mb = 0; mb < 8; ++mb) {
    int ibase = wr * 128 + mb * 16 + 4 * lq;
#pragma unroll
    for (int r = 0; r < 4; ++r) {
      int i = ibase + r;
      int lab = slab[i];
      float cm = sctm[i];
      float f = sft[i];
      {
        float c = acc[mb][0][r] * cn0;
        c = fminf(fmaxf(c, -1.f), 1.f);
        float o = (c > cm) ? c * (newt + c) : c;
        o = (jn0 == lab) ? f : o;
        if (jn0 < C_N) out[(size_t)i * C_N + jn0] = o * S_F;
      }
      {
        float c = acc[mb][1][r] * cn1;
        c = fminf(fmaxf(c, -1.f), 1.f);
        float o = (c > cm) ? c * (newt + c) : c;
        o = (jn1 == lab) ? f : o;
        if (jn1 < C_N) out[(size_t)i * C_N + jn1] = o * S_F;
      }
    }
  }
}

// ---------------- launch -----------------------------------------------------
extern "C" void kernel_launch(void* const* d_in, const int* in_sizes, int n_in,
                              void* d_out, int out_size, void* d_ws, size_t ws_size,
                              hipStream_t stream) {
  (void)in_sizes; (void)n_in; (void)out_size;
  const float* emb = (const float*)d_in[0];
  const int* labels = (const int*)d_in[1];
  const float* Kp = (const float*)d_in[2];
  const float* t_in = (const float*)d_in[3];
  float* out = (float*)d_out;

  char* wsp = (char*)d_ws;
  const size_t KNT_BYTES = (size_t)100096 * D_N * 2;  // 102,498,304
  const size_t NEED = KNT_BYTES + 524288 + 400000 + 4 * 2048 + 4;

  if (ws_size >= NEED) {
    unsigned short* Knt = (unsigned short*)(wsp + 0);
    unsigned short* embn = (unsigned short*)(wsp + KNT_BYTES);
    float* cninv = (float*)(wsp + KNT_BYTES + 524288);
    float* target = (float*)(wsp + KNT_BYTES + 524288 + 400000);
    float* ctm    = (float*)(wsp + KNT_BYTES + 524288 + 400000 + 2048);
    float* ft     = (float*)(wsp + KNT_BYTES + 524288 + 400000 + 2 * 2048);
    float* rinv   = (float*)(wsp + KNT_BYTES + 524288 + 400000 + 3 * 2048);
    float* newt   = (float*)(wsp + KNT_BYTES + 524288 + 400000 + 4 * 2048);

    knorm2_k<<<(C_N + 63) / 64, 512, 0, stream>>>(Kp, cninv, Knt);
    embnorm_k<<<B_N, 128, 0, stream>>>(emb, embn, rinv);
    target_k<<<B_N, 256, 0, stream>>>(emb, Kp, cninv, rinv, labels, target, ctm, ft);
    newt_k<<<1, 512, 0, stream>>>(target, t_in, newt);
    gemm2_k<<<(C_N + 63) / 64, 512, 0, stream>>>(embn, Knt, labels, ctm, ft, newt, out);
  } else {
    unsigned short* embn = (unsigned short*)(wsp + 0);
    float* cninv = (float*)(wsp + 524288);
    float4* part = (float4*)(wsp + 924288);
    float* target = (float*)(wsp + 4124288);
    float* ctm    = (float*)(wsp + 4126336);
    float* ft     = (float*)(wsp + 4128384);
    float* rinv   = (float*)(wsp + 4130432);
    float* newt   = (float*)(wsp + 4132480);

    dim3 cg((JV + 255) / 256, DSPLIT);
    colnorm_part_k<<<cg, 256, 0, stream>>>(Kp, part);
    colnorm_fin_k<<<(JV + 255) / 256, 256, 0, stream>>>(part, (float4*)cninv);
    embnorm_k<<<B_N, 128, 0, stream>>>(emb, embn, rinv);
    target_k<<<B_N, 256, 0, stream>>>(emb, Kp, cninv, rinv, labels, target, ctm, ft);
    newt_k<<<1, 512, 0, stream>>>(target, t_in, newt);
    gemm_k<<<(C_N + BN - 1) / BN, 512, 0, stream>>>(embn, Kp, cninv, labels, ctm, ft, newt, out);
  }
}

// Round 4
// 176.768 us; speedup vs baseline: 2.8523x; 1.0950x over previous
//
#include <hip/hip_runtime.h>
#include <hip/hip_bf16.h>
#include <cstdint>
#include <cstddef>

#define C_N 100000
#define B_N 512
#define D_N 512

#define COS_M_F   0.87758256189037276f
#define SIN_M_F   0.47942553860420301f
#define THRESH_F  (-0.87758256189037276f)
#define MM_F      0.23971276930210150f
#define S_F       64.0f

typedef __attribute__((ext_vector_type(8))) short short8;
typedef __attribute__((ext_vector_type(4))) float f32x4;

__device__ __forceinline__ unsigned short f2bf(float f) {
  unsigned u = __float_as_uint(f);
  u = u + 0x7fffu + ((u >> 16) & 1u);
  return (unsigned short)(u >> 16);
}

__device__ __forceinline__ float wave_sum(float v) {
#pragma unroll
  for (int o = 32; o > 0; o >>= 1) v += __shfl_down(v, o, 64);
  return v;
}

__device__ __forceinline__ void lds_load16(const void* g, void* l) {
  __builtin_amdgcn_global_load_lds(
      (const __attribute__((address_space(1))) unsigned int*)g,
      (__attribute__((address_space(3))) unsigned int*)l, 16, 0, 0);
}

// ---------------- kernel 2: embedding row normalize -> bf16 ------------------
__global__ void embnorm_k(const float* __restrict__ emb, unsigned short* __restrict__ embn,
                          float* __restrict__ rinv) {
  int row = blockIdx.x;
  int t = threadIdx.x;  // 128 threads, one float4 each
  float4 v = ((const float4*)(emb + (size_t)row * D_N))[t];
  float ss = v.x * v.x + v.y * v.y + v.z * v.z + v.w * v.w;
  ss = wave_sum(ss);
  __shared__ float red[2];
  if ((t & 63) == 0) red[t >> 6] = ss;
  __syncthreads();
  float tot = red[0] + red[1];
  float ri = rsqrtf(tot);
  if (t == 0) rinv[row] = ri;
  ushort4 o;
  o.x = f2bf(v.x * ri); o.y = f2bf(v.y * ri); o.z = f2bf(v.z * ri); o.w = f2bf(v.w * ri);
  ((ushort4*)(embn + (size_t)row * D_N))[t] = o;
}

// ---------------- kernel 3: target logit; computes label-col norm itself -----
__global__ void target2_k(const float* __restrict__ emb, const float* __restrict__ Kp,
                          const float* __restrict__ rinv, const int* __restrict__ labels,
                          float* __restrict__ target, float* __restrict__ ctm,
                          float* __restrict__ ft) {
  int row = blockIdx.x;
  int t = threadIdx.x;  // 256
  int lab = labels[row];
  float p = 0.f, ss = 0.f;
  for (int d = t; d < D_N; d += 256) {
    float kv = Kp[(size_t)d * C_N + lab];
    p = fmaf(emb[(size_t)row * D_N + d], kv, p);
    ss = fmaf(kv, kv, ss);
  }
  p = wave_sum(p);
  ss = wave_sum(ss);
  __shared__ float redp[4], reds[4];
  if ((t & 63) == 0) { redp[t >> 6] = p; reds[t >> 6] = ss; }
  __syncthreads();
  if (t == 0) {
    float dot = redp[0] + redp[1] + redp[2] + redp[3];
    float sums = reds[0] + reds[1] + reds[2] + reds[3];
    float tg = dot * rinv[row] * rsqrtf(fmaxf(sums, 1e-30f));
    tg = fminf(fmaxf(tg, -1.f), 1.f);
    float st = sqrtf(fmaxf(1.f - tg * tg, 0.f));
    float cm = tg * COS_M_F - st * SIN_M_F;
    float f = (tg > THRESH_F) ? cm : (tg - MM_F);
    target[row] = tg;
    ctm[row] = cm;
    ft[row] = f;
  }
}

// ---------------- kernel 4: new_t reduction ----------------------------------
__global__ void newt_k(const float* __restrict__ target, const float* __restrict__ t_in,
                       float* __restrict__ newt) {
  int t = threadIdx.x;  // 512
  float v = target[t];
  v = wave_sum(v);
  __shared__ float red[8];
  if ((t & 63) == 0) red[t >> 6] = v;
  __syncthreads();
  if (t == 0) {
    float s = 0.f;
#pragma unroll
    for (int i = 0; i < 8; ++i) s += red[i];
    *newt = 0.01f * (s / (float)B_N) + 0.99f * t_in[0];
  }
}

// ---------------- kernel G3: fused colnorm + MFMA GEMM + epilogue ------------
// Per block: 64 output cols. Phase 1: read K[:, j0:j0+64] f32 (128KB), colnorm
// via LDS reduce, scale+bf16 in-register, ds_write full 64KB B tile in the
// verified swizzled fragment layout. Phase 2: 16-iter K-loop, A double-buffered
// via global_load_lds from L2-resident embn, B LDS-resident. Fused epilogue
// with nontemporal f32 stores.
// LDS map: [0,64K) B tiles (16 x 4KB); [64K,128K) A dbuf (2 x 32KB; first 8KB
// of buf0 aliased as ssum during phase 1); [128K,+) slab/sctm/sft/cns.
__launch_bounds__(512, 2)
__global__ void gemm3_k(const float* __restrict__ Kp,
                        const unsigned short* __restrict__ embn,
                        const int* __restrict__ labels,
                        const float* __restrict__ ctm, const float* __restrict__ ft,
                        const float* __restrict__ newt_p, float* __restrict__ out) {
  __shared__ __align__(16) char lds[131072 + 3 * 2048 + 256];
  unsigned short* Bl = (unsigned short*)lds;
  unsigned short* Albase = (unsigned short*)(lds + 65536);
  float* ssum = (float*)(lds + 65536);  // [32][64] aliased with A buf0
  int*   slab = (int*)(lds + 131072);
  float* sctm = (float*)(lds + 131072 + 2048);
  float* sft  = (float*)(lds + 131072 + 4096);
  float* cns  = (float*)(lds + 131072 + 6144);

  const int t = threadIdx.x;
  const int j0 = blockIdx.x * 64;

  slab[t] = labels[t];
  sctm[t] = ctm[t];
  sft[t]  = ft[t];

  // ---- phase 1: load K columns (f32, coalesced float4), column sum-squares --
  const int jq = t & 15;   // 16 float4-column groups
  const int dr = t >> 4;   // 32 d-groups of 16
  const int jcol = min((j0 >> 2) + jq, (C_N >> 2) - 1);
  const float4* __restrict__ Kv = (const float4*)Kp;
  float4 v[16];
#pragma unroll
  for (int i = 0; i < 16; ++i)
    v[i] = Kv[(size_t)(dr * 16 + i) * (C_N / 4) + jcol];

  float s0 = 0.f, s1 = 0.f, s2 = 0.f, s3 = 0.f;
#pragma unroll
  for (int i = 0; i < 16; ++i) {
    s0 = fmaf(v[i].x, v[i].x, s0);
    s1 = fmaf(v[i].y, v[i].y, s1);
    s2 = fmaf(v[i].z, v[i].z, s2);
    s3 = fmaf(v[i].w, v[i].w, s3);
  }
  ssum[dr * 64 + jq * 4 + 0] = s0;
  ssum[dr * 64 + jq * 4 + 1] = s1;
  ssum[dr * 64 + jq * 4 + 2] = s2;
  ssum[dr * 64 + jq * 4 + 3] = s3;
  __syncthreads();
  if (t < 64) {
    float s = 0.f;
#pragma unroll
    for (int d = 0; d < 32; ++d) s += ssum[d * 64 + t];
    cns[t] = rsqrtf(fmaxf(s, 1e-30f));
  }
  __syncthreads();

  // ---- phase 2: issue A prologue loads, then pack B into swizzled LDS ------
  const int l = t & 63, w = t >> 6;
  const int sidx = (l & 7) ^ (l >> 3);
  const int r0 = ((l >> 3) << 1) | (sidx >> 2);
  const int kc8 = (sidx & 3) * 8;
  const unsigned short* asrc = embn + (size_t)(w * 64 + r0) * D_N + kc8;

#pragma unroll
  for (int p = 0; p < 4; ++p)
    lds_load16(asrc + p * 16 * D_N, Albase + w * 2048 + p * 512);

  // B pack: thread covers cols n = jq*4+cc, d = dr*16 + 0..15.
  // Layout: byte = itile*4096 + (n>>1)*128 + ((((n&1)<<2)|c) ^ ((n>>1)&7))*16
  {
    const float rc0 = cns[jq * 4 + 0];
    const float rc1 = cns[jq * 4 + 1];
    const float rc2 = cns[jq * 4 + 2];
    const float rc3 = cns[jq * 4 + 3];
    const int itile = dr >> 1;
    const int cbase = (dr & 1) * 2;
#pragma unroll
    for (int cc = 0; cc < 4; ++cc) {
      const int n = jq * 4 + cc;
      const int rowp = n >> 1;
      const int nb = (n & 1) << 2;
      const int x7 = rowp & 7;
      const float rc = (cc == 0) ? rc0 : (cc == 1) ? rc1 : (cc == 2) ? rc2 : rc3;
#pragma unroll
      for (int h = 0; h < 2; ++h) {
        unsigned w0 = (unsigned)f2bf(v[h * 8 + 0][cc] * rc) | ((unsigned)f2bf(v[h * 8 + 1][cc] * rc) << 16);
        unsigned w1 = (unsigned)f2bf(v[h * 8 + 2][cc] * rc) | ((unsigned)f2bf(v[h * 8 + 3][cc] * rc) << 16);
        unsigned w2 = (unsigned)f2bf(v[h * 8 + 4][cc] * rc) | ((unsigned)f2bf(v[h * 8 + 5][cc] * rc) << 16);
        unsigned w3 = (unsigned)f2bf(v[h * 8 + 6][cc] * rc) | ((unsigned)f2bf(v[h * 8 + 7][cc] * rc) << 16);
        char* dst = (char*)Bl + itile * 4096 + rowp * 128 + ((nb | (cbase + h)) ^ x7) * 16;
        *(uint4*)dst = make_uint4(w0, w1, w2, w3);
      }
    }
  }
  __syncthreads();  // drains B ds_writes AND A prologue vmcnt

  // ---- phase 3: K-loop (A dbuf via global_load_lds, B resident) -------------
  const int wr = w >> 1, wc = w & 1;
  const int lq = l >> 4, lr = l & 15;
  const int s16 = ((((lr & 1) << 2) | lq) ^ (lr >> 1)) << 4;
  const int rh = lr >> 1;
  const float newt = *newt_p;

  f32x4 acc[8][2];
#pragma unroll
  for (int mb = 0; mb < 8; ++mb) {
    acc[mb][0] = 0;
    acc[mb][1] = 0;
  }

#pragma unroll
  for (int it = 0; it < 16; ++it) {
    const int cur = it & 1, nxt = cur ^ 1;
    if (it < 15) {
      const int k0 = (it + 1) * 32;
#pragma unroll
      for (int p = 0; p < 4; ++p)
        lds_load16(asrc + p * 16 * D_N + k0, Albase + nxt * 16384 + w * 2048 + p * 512);
    }
    const char* Ab = (const char*)(Albase + cur * 16384);
    const char* Bt = (const char*)Bl + it * 4096;
    short8 b0 = *(const short8*)(Bt + ((wc * 16 + 0 + rh) << 7) + s16);
    short8 b1 = *(const short8*)(Bt + ((wc * 16 + 8 + rh) << 7) + s16);
#pragma unroll
    for (int mb = 0; mb < 8; ++mb) {
      short8 a = *(const short8*)(Ab + ((wr * 64 + mb * 8 + rh) << 7) + s16);
      acc[mb][0] = __builtin_amdgcn_mfma_f32_16x16x32_bf16(a, b0, acc[mb][0], 0, 0, 0);
      acc[mb][1] = __builtin_amdgcn_mfma_f32_16x16x32_bf16(a, b1, acc[mb][1], 0, 0, 0);
    }
    __syncthreads();
  }

  // ---- epilogue (B pre-normalized; nontemporal stores) ----------------------
  const int jn0 = j0 + wc * 32 + lr;
  const int jn1 = jn0 + 16;
#pragma unroll
  for (int mb = 0; mb < 8; ++mb) {
    int ibase = wr * 128 + mb * 16 + 4 * lq;
#pragma unroll
    for (int r = 0; r < 4; ++r) {
      int i = ibase + r;
      int lab = slab[i];
      float cm = sctm[i];
      float f = sft[i];
      {
        float c = fminf(fmaxf(acc[mb][0][r], -1.f), 1.f);
        float o = (c > cm) ? c * (newt + c) : c;
        o = (jn0 == lab) ? f : o;
        if (jn0 < C_N)
          __builtin_nontemporal_store(o * S_F, &out[(size_t)i * C_N + jn0]);
      }
      {
        float c = fminf(fmaxf(acc[mb][1][r], -1.f), 1.f);
        float o = (c > cm) ? c * (newt + c) : c;
        o = (jn1 == lab) ? f : o;
        if (jn1 < C_N)
          __builtin_nontemporal_store(o * S_F, &out[(size_t)i * C_N + jn1]);
      }
    }
  }
}

// ---------------- launch -----------------------------------------------------
extern "C" void kernel_launch(void* const* d_in, const int* in_sizes, int n_in,
                              void* d_out, int out_size, void* d_ws, size_t ws_size,
                              hipStream_t stream) {
  (void)in_sizes; (void)n_in; (void)out_size; (void)ws_size;
  const float* emb = (const float*)d_in[0];
  const int* labels = (const int*)d_in[1];
  const float* Kp = (const float*)d_in[2];
  const float* t_in = (const float*)d_in[3];
  float* out = (float*)d_out;

  char* wsp = (char*)d_ws;
  unsigned short* embn = (unsigned short*)(wsp + 0);   // 524288 B
  float* target = (float*)(wsp + 524288);              // 2048 B
  float* ctm    = (float*)(wsp + 526336);              // 2048 B
  float* ft     = (float*)(wsp + 528384);              // 2048 B
  float* rinv   = (float*)(wsp + 530432);              // 2048 B
  float* newt   = (float*)(wsp + 532480);              // 4 B

  embnorm_k<<<B_N, 128, 0, stream>>>(emb, embn, rinv);
  target2_k<<<B_N, 256, 0, stream>>>(emb, Kp, rinv, labels, target, ctm, ft);
  newt_k<<<1, 512, 0, stream>>>(target, t_in, newt);
  gemm3_k<<<(C_N + 63) / 64, 512, 0, stream>>>(Kp, embn, labels, ctm, ft, newt, out);
}